// Round 6
// baseline (179.288 us; speedup 1.0000x reference)
//
#include <hip/hip_runtime.h>

#define S_LEN 2048
#define D_MODEL 512
#define NHEAD 8
#define BATCH 2

typedef __attribute__((ext_vector_type(8))) short bf16x8;
typedef __attribute__((ext_vector_type(4))) float f32x4;

__device__ __forceinline__ unsigned short f2bf(float f) {
    union { float f; unsigned u; } v; v.f = f;
    unsigned u = v.u + 0x7FFFu + ((v.u >> 16) & 1u);   // RNE
    return (unsigned short)(u >> 16);
}

__device__ __forceinline__ bf16x8 pack8(float4 a, float4 b) {
    bf16x8 r;
    r[0] = (short)f2bf(a.x); r[1] = (short)f2bf(a.y);
    r[2] = (short)f2bf(a.z); r[3] = (short)f2bf(a.w);
    r[4] = (short)f2bf(b.x); r[5] = (short)f2bf(b.y);
    r[6] = (short)f2bf(b.z); r[7] = (short)f2bf(b.w);
    return r;
}

// async global->LDS, 16B per lane, LDS dest = wave-uniform base + lane*16
__device__ __forceinline__ void gl_lds16(const unsigned short* g, unsigned short* l) {
    __builtin_amdgcn_global_load_lds(
        (const __attribute__((address_space(1))) void*)g,
        (__attribute__((address_space(3))) void*)l,
        16, 0, 0);
}

// --------------------------------------------------------- projection GEMM --
// Fused fp32->bf16 convert + GEMM. 128(s) x 256(f) tile, BK=64, register-
// prefetched fp32 loads, VALU convert, ds_write into padded (stride-76) LDS.
// Blocks (x<2, y==0, z==0) also compute lens from the pad masks.
// No early-exit on padded s-tiles: at ~1.5 blocks/CU they cost no wall time,
// and dropping the lens dependency lets everything run in one kernel.
// z=0 -> Q (prescaled 0.125) [bh][s][dk]; z=1 -> K; z=2 -> V^T [bh][dk][s]
__global__ __launch_bounds__(256, 1) void proj_gemm(
    const float* __restrict__ inQ, const float* __restrict__ inK, const float* __restrict__ inV,
    const float* __restrict__ WQ,  const float* __restrict__ WK,  const float* __restrict__ WV,
    const float* __restrict__ bQ,  const float* __restrict__ bK,  const float* __restrict__ bV,
    const int* __restrict__ rpm,   const int* __restrict__ cpm,
    unsigned short* __restrict__ Qg, unsigned short* __restrict__ Kg,
    unsigned short* __restrict__ VTg, int* __restrict__ lens)
{
    __shared__ __align__(16) unsigned short XldP[128 * 76];
    __shared__ __align__(16) unsigned short WldP[256 * 76];

    const int z = blockIdx.z;
    const int tileS = blockIdx.x * 128;
    const int fh = blockIdx.y * 256;
    const int t = threadIdx.x;

    // ---- lens (2 designated blocks; LDS scratch aliases XldP, done before staging)
    if (blockIdx.x < 2 && blockIdx.y == 0 && z == 0) {
        int* red = (int*)XldP;
        const int b = blockIdx.x;
        int sr = 0, sc2 = 0;
        for (int i = t; i < S_LEN; i += 256) {
            sr  += rpm[b * S_LEN + i];
            sc2 += cpm[b * S_LEN + i];
        }
        red[t] = sr;
        __syncthreads();
        for (int off = 128; off > 0; off >>= 1) {
            if (t < off) red[t] += red[t + off];
            __syncthreads();
        }
        if (t == 0) lens[b * 2 + 0] = red[0];
        __syncthreads();
        red[t] = sc2;
        __syncthreads();
        for (int off = 128; off > 0; off >>= 1) {
            if (t < off) red[t] += red[t + off];
            __syncthreads();
        }
        if (t == 0) lens[b * 2 + 1] = red[0];
    }

    const float* X    = (z == 0) ? inQ : (z == 1) ? inK : inV;
    const float* W    = (z == 0) ? WQ  : (z == 1) ? WK  : WV;
    const float* bias = (z == 0) ? bQ  : (z == 1) ? bK  : bV;

    const int wv = t >> 6, lane = t & 63, l15 = lane & 15, quad = lane >> 4;

    // staging assignment: X row = t>>1 (2 threads/row, 32 cols each);
    //                     W row = t (1 thread/row, 64 cols)
    const int xrow = t >> 1, xcol = (t & 1) * 32;
    const float* gX = X + (size_t)(tileS + xrow) * 512 + xcol;
    const float* gW = W + (size_t)(fh + t) * 512;

    float4 xr[8], wr[16];
    #pragma unroll
    for (int j = 0; j < 8; ++j)  xr[j] = *(const float4*)(gX + j * 4);
    #pragma unroll
    for (int j = 0; j < 16; ++j) wr[j] = *(const float4*)(gW + j * 4);

    f32x4 acc[4][8] = {};

    unsigned short* xd = XldP + xrow * 76 + xcol;
    unsigned short* wd = WldP + t * 76;

    for (int kk = 0; kk < 8; ++kk) {
        __syncthreads();                       // prev chunk's frag reads done
        #pragma unroll
        for (int j = 0; j < 4; ++j)
            *(bf16x8*)(xd + j * 8) = pack8(xr[2 * j], xr[2 * j + 1]);
        #pragma unroll
        for (int j = 0; j < 8; ++j)
            *(bf16x8*)(wd + j * 8) = pack8(wr[2 * j], wr[2 * j + 1]);
        __syncthreads();                       // staged data visible
        if (kk < 7) {                          // prefetch next chunk (async under MFMA)
            const int k0 = (kk + 1) * 64;
            #pragma unroll
            for (int j = 0; j < 8; ++j)  xr[j] = *(const float4*)(gX + k0 + j * 4);
            #pragma unroll
            for (int j = 0; j < 16; ++j) wr[j] = *(const float4*)(gW + k0 + j * 4);
        }
        #pragma unroll
        for (int kk2 = 0; kk2 < 2; ++kk2) {
            bf16x8 wf[4], xf[8];
            #pragma unroll
            for (int i = 0; i < 4; ++i)
                wf[i] = *(const bf16x8*)(WldP + (wv * 64 + i * 16 + l15) * 76 + kk2 * 32 + quad * 8);
            #pragma unroll
            for (int st = 0; st < 8; ++st)
                xf[st] = *(const bf16x8*)(XldP + (st * 16 + l15) * 76 + kk2 * 32 + quad * 8);
            #pragma unroll
            for (int i = 0; i < 4; ++i)
                #pragma unroll
                for (int st = 0; st < 8; ++st)
                    acc[i][st] = __builtin_amdgcn_mfma_f32_16x16x32_bf16(
                        wf[i], xf[st], acc[i][st], 0, 0, 0);
        }
    }

    const float oscale = (z == 0) ? 0.125f : 1.0f;   // fold 1/sqrt(dk) into Q
    #pragma unroll
    for (int i = 0; i < 4; ++i) {
        const int f = fh + wv * 64 + i * 16 + quad * 4;
        const int h = f >> 6, dk = f & 63;
        const float b0 = bias[f], b1 = bias[f + 1], b2 = bias[f + 2], b3 = bias[f + 3];
        #pragma unroll
        for (int st = 0; st < 8; ++st) {
            const int s = tileS + st * 16 + l15;
            const int bb = s >> 11, seq = s & 2047;
            const f32x4 a = acc[i][st];
            if (z <= 1) {
                unsigned short* dst = ((z == 0) ? Qg : Kg)
                    + ((size_t)((bb * 8 + h) * 2048 + seq)) * 64 + dk;
                ushort4 u;
                u.x = f2bf((a[0] + b0) * oscale); u.y = f2bf((a[1] + b1) * oscale);
                u.z = f2bf((a[2] + b2) * oscale); u.w = f2bf((a[3] + b3) * oscale);
                *(ushort4*)dst = u;
            } else {
                unsigned short* dst = VTg
                    + ((size_t)((bb * 8 + h) * 64 + dk)) * 2048 + seq;
                dst[0]    = f2bf(a[0] + b0);
                dst[2048] = f2bf(a[1] + b1);
                dst[4096] = f2bf(a[2] + b2);
                dst[6144] = f2bf(a[3] + b3);
            }
        }
    }
}

// ----------------------------------------------------------- attention ------
// Flash-decoding, 4 waves split the kv loop; per-wave LDS staging via
// global_load_lds, no block barriers in the loop (explicit s_waitcnt).
__global__ __launch_bounds__(256) void attn_kernel(
    const unsigned short* __restrict__ Qg, const unsigned short* __restrict__ Kg,
    const unsigned short* __restrict__ VTg, const int* __restrict__ lens,
    unsigned short* __restrict__ AO)
{
    __shared__ __align__(16) char smem[32768 + 9216 + 512];
    unsigned short* stage = (unsigned short*)smem;              // 4 x 4096 shorts
    unsigned short* Plb   = (unsigned short*)(smem + 32768);    // 4 x 16 x 72
    float* Ml = (float*)(smem + 32768 + 9216);                  // 64
    float* Ll = Ml + 64;                                        // 64

    const int t = threadIdx.x;
    const int wv = t >> 6, lane = t & 63, l15 = lane & 15, quad = lane >> 4;
    const int bh = blockIdx.y;
    const int b = bh >> 3, h = bh & 7;
    const int q0 = blockIdx.x * 16;
    const int rl = lens[b * 2], cl = lens[b * 2 + 1];

    if (q0 >= rl) {                            // fully masked rows -> zeros
        const int row = t >> 4, cg = t & 15;
        ushort4 zz = {0, 0, 0, 0};
        *(ushort4*)(AO + ((size_t)(b * 2048 + q0 + row)) * 512 + h * 64 + cg * 4) = zz;
        return;
    }

    const unsigned short* Qrow = Qg + ((size_t)(bh * 2048 + q0 + l15)) * 64;
    const bf16x8 aq0 = *(const bf16x8*)(Qrow + quad * 8);
    const bf16x8 aq1 = *(const bf16x8*)(Qrow + 32 + quad * 8);

    unsigned short* stw = stage + wv * 4096;   // this wave's 8 KB tile buffer
    unsigned short* pb  = Plb + wv * (16 * 72);

    const int sro = lane >> 3;                     // staging row-in-group
    const int sc8 = ((lane & 7) ^ sro) * 8;        // swizzled chunk (shorts)
    const int kg_off  = sro * 64 + sc8;            // K per-lane src offset
    const int vtg_off = sro * 2048 + sc8;          // V^T per-lane src offset
    const int sw7 = l15 & 7;

    f32x4 oacc[4] = {};
    float m_[4], l_[4];
    #pragma unroll
    for (int r = 0; r < 4; ++r) { m_[r] = -__builtin_inff(); l_[r] = 0.f; }

    const int q_end = q0 + 16;
    const int kv_max = (cl < q_end) ? cl : q_end;
    const int ntiles = (kv_max + 63) >> 6;
    const int qrow0 = q0 + quad * 4;

    for (int kt = wv; kt < ntiles; kt += 4) {
        const int kv0 = kt * 64;

        {
            const unsigned short* kg = Kg + ((size_t)(bh * 2048 + kv0)) * 64 + kg_off;
            #pragma unroll
            for (int j = 0; j < 8; ++j)
                gl_lds16(kg + j * 512, stw + j * 512);
        }
        __builtin_amdgcn_s_waitcnt(0x0070);    // vmcnt(0)+lgkmcnt(0): K staged

        f32x4 sc[4] = {};
        #pragma unroll
        for (int ct = 0; ct < 4; ++ct) {
            const unsigned short* krow = stw + (ct * 16 + l15) * 64;
            const bf16x8 kf0 = *(const bf16x8*)(krow + ((quad    ) ^ sw7) * 8);
            const bf16x8 kf1 = *(const bf16x8*)(krow + ((quad + 4) ^ sw7) * 8);
            sc[ct] = __builtin_amdgcn_mfma_f32_16x16x32_bf16(aq0, kf0, sc[ct], 0, 0, 0);
            sc[ct] = __builtin_amdgcn_mfma_f32_16x16x32_bf16(aq1, kf1, sc[ct], 0, 0, 0);
        }
        __builtin_amdgcn_s_waitcnt(0x0070);    // K frag ds_reads done -> region free

        {
            const unsigned short* vg = VTg + ((size_t)(bh * 64)) * 2048 + kv0 + vtg_off;
            #pragma unroll
            for (int j = 0; j < 8; ++j)
                gl_lds16(vg + j * 16384, stw + j * 512);
        }

        const bool full = (kv0 + 64 <= q0) && (kv0 + 64 <= cl) && (q_end <= rl);

        #pragma unroll
        for (int r = 0; r < 4; ++r) {
            const int q = qrow0 + r;
            float mx = -__builtin_inff();
            if (full) {
                #pragma unroll
                for (int ct = 0; ct < 4; ++ct) mx = fmaxf(mx, sc[ct][r]);
            } else {
                #pragma unroll
                for (int ct = 0; ct < 4; ++ct) {
                    const int kv = kv0 + ct * 16 + l15;
                    float s = sc[ct][r];
                    const bool valid = (q < rl) && (kv < cl) && (kv <= q);
                    s = valid ? s : -__builtin_inff();
                    sc[ct][r] = s;
                    mx = fmaxf(mx, s);
                }
            }
            mx = fmaxf(mx, __shfl_xor(mx, 1, 16));
            mx = fmaxf(mx, __shfl_xor(mx, 2, 16));
            mx = fmaxf(mx, __shfl_xor(mx, 4, 16));
            mx = fmaxf(mx, __shfl_xor(mx, 8, 16));

            const float mold = m_[r];
            const float mnew = fmaxf(mold, mx);
            const float alpha = (mold == -__builtin_inff()) ? 0.f : __expf(mold - mnew);
            float psum = 0.f;
            #pragma unroll
            for (int ct = 0; ct < 4; ct++) {
                const float sv = sc[ct][r];
                const float p = (mnew == -__builtin_inff()) ? 0.f : __expf(sv - mnew);
                sc[ct][r] = p;
                psum += p;
            }
            psum += __shfl_xor(psum, 1, 16);
            psum += __shfl_xor(psum, 2, 16);
            psum += __shfl_xor(psum, 4, 16);
            psum += __shfl_xor(psum, 8, 16);
            l_[r] = alpha * l_[r] + psum;
            m_[r] = mnew;
            #pragma unroll
            for (int ct = 0; ct < 4; ct++) oacc[ct][r] *= alpha;
        }

        // P: C-layout -> A-layout via padded per-wave LDS (stride 72 shorts)
        #pragma unroll
        for (int ct = 0; ct < 4; ++ct) {
            #pragma unroll
            for (int r = 0; r < 4; ++r)
                pb[(quad * 4 + r) * 72 + ct * 16 + l15] = f2bf(sc[ct][r]);
        }
        const bf16x8 pf0 = *(const bf16x8*)(pb + l15 * 72 + quad * 8);
        const bf16x8 pf1 = *(const bf16x8*)(pb + l15 * 72 + 32 + quad * 8);

        __builtin_amdgcn_s_waitcnt(0x0070);    // V^T staged (and P ds ops done)
        #pragma unroll
        for (int ct = 0; ct < 4; ++ct) {
            const unsigned short* vrow = stw + (ct * 16 + l15) * 64;
            const bf16x8 vf0 = *(const bf16x8*)(vrow + ((quad    ) ^ sw7) * 8);
            const bf16x8 vf1 = *(const bf16x8*)(vrow + ((quad + 4) ^ sw7) * 8);
            oacc[ct] = __builtin_amdgcn_mfma_f32_16x16x32_bf16(pf0, vf0, oacc[ct], 0, 0, 0);
            oacc[ct] = __builtin_amdgcn_mfma_f32_16x16x32_bf16(pf1, vf1, oacc[ct], 0, 0, 0);
        }
    }

    if (l15 == 0) {
        #pragma unroll
        for (int r = 0; r < 4; ++r) {
            Ml[wv * 16 + quad * 4 + r] = m_[r];
            Ll[wv * 16 + quad * 4 + r] = l_[r];
        }
    }
    __syncthreads();                           // all waves done with staging

    float* Po = (float*)smem;                  // O partials alias staging region
    #pragma unroll
    for (int ct = 0; ct < 4; ++ct) {
        #pragma unroll
        for (int r = 0; r < 4; ++r)
            Po[wv * 1088 + (quad * 4 + r) * 68 + ct * 16 + l15] = oacc[ct][r];
    }
    __syncthreads();

    const int row = t >> 4, cg = t & 15;
    float mw[4];
    float mstar = -__builtin_inff();
    #pragma unroll
    for (int w = 0; w < 4; ++w) {
        mw[w] = Ml[w * 16 + row];
        mstar = fmaxf(mstar, mw[w]);
    }
    f32x4 o = {};
    if (mstar != -__builtin_inff()) {
        float lst = 0.f;
        #pragma unroll
        for (int w = 0; w < 4; ++w) {
            const float sw = (mw[w] == -__builtin_inff()) ? 0.f : __expf(mw[w] - mstar);
            lst += sw * Ll[w * 16 + row];
            const f32x4 pv = *(const f32x4*)&Po[w * 1088 + row * 68 + cg * 4];
            o[0] += sw * pv[0]; o[1] += sw * pv[1];
            o[2] += sw * pv[2]; o[3] += sw * pv[3];
        }
        const float inv = (lst > 0.f) ? 1.f / lst : 0.f;
        o[0] *= inv; o[1] *= inv; o[2] *= inv; o[3] *= inv;
    }
    ushort4 u;
    u.x = f2bf(o[0]); u.y = f2bf(o[1]); u.z = f2bf(o[2]); u.w = f2bf(o[3]);
    *(ushort4*)(AO + ((size_t)(b * 2048 + q0 + row)) * 512 + h * 64 + cg * 4) = u;
}

// ------------------------------------------------------------- output GEMM --
// AO (bf16) staged via gl_lds dbuf; W_O converted fp32->bf16 on the fly into
// padded (stride-76) LDS with register prefetch.
__global__ __launch_bounds__(256) void out_gemm(
    const unsigned short* __restrict__ AO, const float* __restrict__ WO,
    const float* __restrict__ bO, const int* __restrict__ lens, float* __restrict__ out)
{
    __shared__ __align__(16) unsigned short Xld[2][8192];
    __shared__ __align__(16) unsigned short WldP[128 * 76];

    const int tileS = blockIdx.x * 128;
    const int tileF = blockIdx.y * 128;
    const int bb0 = tileS >> 11;
    const int rl = lens[bb0 * 2];
    const int t = threadIdx.x;

    if ((tileS & 2047) >= rl) {                // padded rows: out = bias
        const int r0 = t >> 2;
        const int cg = (t & 3) * 32;
        float4 bv[8];
        #pragma unroll
        for (int j = 0; j < 8; ++j) bv[j] = *(const float4*)(bO + tileF + cg + j * 4);
        #pragma unroll
        for (int i = 0; i < 2; ++i) {
            float* orow = out + (size_t)(tileS + i * 64 + r0) * 512 + tileF + cg;
            #pragma unroll
            for (int j = 0; j < 8; ++j) *(float4*)(orow + j * 4) = bv[j];
        }
        return;
    }

    const int wv = t >> 6, lane = t & 63, l15 = lane & 15, quad = lane >> 4;
    const int ro = lane >> 3;
    const int lc8 = ((lane & 7) ^ ro) * 8;

    const unsigned short* gX = AO + (size_t)(tileS + wv * 32 + ro) * 512 + lc8;
    const int wvo = wv * 2048;

    const int wrow = t >> 1, wcol = (t & 1) * 32;
    const float* gWf = WO + (size_t)(tileF + wrow) * 512 + wcol;
    unsigned short* wd = WldP + wrow * 76 + wcol;

    const int f_off = (wv & 1) * 64, s_off = (wv >> 1) * 64;
    const int swk = l15 & 7;

    f32x4 acc[4][4] = {};
    float4 wr[8];

    // prologue: X chunk0 via gl_lds, W chunk0 into regs
    #pragma unroll
    for (int j = 0; j < 4; ++j)
        gl_lds16(gX + j * 4096, &Xld[0][wvo + j * 512]);
    #pragma unroll
    for (int j = 0; j < 8; ++j) wr[j] = *(const float4*)(gWf + j * 4);

    for (int kk = 0; kk < 8; ++kk) {
        __syncthreads();                       // drains X gl_lds; prev reads done
        #pragma unroll
        for (int j = 0; j < 4; ++j)
            *(bf16x8*)(wd + j * 8) = pack8(wr[2 * j], wr[2 * j + 1]);
        __syncthreads();
        if (kk < 7) {
            const int k0 = (kk + 1) * 64;
            const int nb = (kk + 1) & 1;
            #pragma unroll
            for (int j = 0; j < 4; ++j)
                gl_lds16(gX + k0 + j * 4096, &Xld[nb][wvo + j * 512]);
            #pragma unroll
            for (int j = 0; j < 8; ++j) wr[j] = *(const float4*)(gWf + k0 + j * 4);
        }
        const unsigned short* Xb = Xld[kk & 1];
        #pragma unroll
        for (int kk2 = 0; kk2 < 2; ++kk2) {
            bf16x8 wf[4], xf[4];
            #pragma unroll
            for (int i = 0; i < 4; ++i) {
                wf[i] = *(const bf16x8*)(WldP + (f_off + i * 16 + l15) * 76 + kk2 * 32 + quad * 8);
                const int rx = s_off + i * 16 + l15;
                xf[i] = *(const bf16x8*)(Xb + rx * 64 + ((kk2 * 4 + quad) ^ swk) * 8);
            }
            #pragma unroll
            for (int ft = 0; ft < 4; ++ft)
                #pragma unroll
                for (int st = 0; st < 4; ++st)
                    acc[ft][st] = __builtin_amdgcn_mfma_f32_16x16x32_bf16(
                        wf[ft], xf[st], acc[ft][st], 0, 0, 0);
        }
    }

    #pragma unroll
    for (int ft = 0; ft < 4; ++ft) {
        const int f = tileF + f_off + ft * 16 + quad * 4;
        const float4 bv = *(const float4*)(bO + f);
        #pragma unroll
        for (int st = 0; st < 4; ++st) {
            const int s = tileS + s_off + st * 16 + l15;
            float4 o;
            o.x = acc[ft][st][0] + bv.x;
            o.y = acc[ft][st][1] + bv.y;
            o.z = acc[ft][st][2] + bv.z;
            o.w = acc[ft][st][3] + bv.w;
            *(float4*)(out + (size_t)s * 512 + f) = o;
        }
    }
}

// -------------------------------------------------------------- launch ------
extern "C" void kernel_launch(void* const* d_in, const int* in_sizes, int n_in,
                              void* d_out, int out_size, void* d_ws, size_t ws_size,
                              hipStream_t stream)
{
    const float* inQ = (const float*)d_in[0];
    const float* inK = (const float*)d_in[1];
    const float* inV = (const float*)d_in[2];
    const int*   rpm = (const int*)d_in[3];
    const int*   cpm = (const int*)d_in[4];
    const float* WQ  = (const float*)d_in[5];
    const float* bQ  = (const float*)d_in[6];
    const float* WK  = (const float*)d_in[7];
    const float* bK  = (const float*)d_in[8];
    const float* WV  = (const float*)d_in[9];
    const float* bV  = (const float*)d_in[10];
    const float* WO  = (const float*)d_in[11];
    const float* bO  = (const float*)d_in[12];
    float* out = (float*)d_out;

    char* ws = (char*)d_ws;
    unsigned short* Qg  = (unsigned short*)(ws);                 // 4 MB
    unsigned short* Kg  = (unsigned short*)(ws + 4194304);       // 4 MB
    unsigned short* VTg = (unsigned short*)(ws + 8388608);       // 4 MB
    unsigned short* AO  = (unsigned short*)(ws + 12582912);      // 4 MB
    int* lens           = (int*)(ws + 16777216);

    proj_gemm<<<dim3(32, 2, 3), dim3(256), 0, stream>>>(
        inQ, inK, inV, WQ, WK, WV, bQ, bK, bV, rpm, cpm, Qg, Kg, VTg, lens);
    attn_kernel<<<dim3(128, 16), dim3(256), 0, stream>>>(Qg, Kg, VTg, lens, AO);
    out_gemm<<<dim3(32, 4), dim3(256), 0, stream>>>(AO, WO, bO, lens, out);
}

// Round 7
// 150.544 us; speedup vs baseline: 1.1909x; 1.1909x over previous
//
#include <hip/hip_runtime.h>

#define S_LEN 2048
#define D_MODEL 512
#define NHEAD 8
#define BATCH 2

typedef __attribute__((ext_vector_type(8))) short bf16x8;
typedef __attribute__((ext_vector_type(4))) float f32x4;

__device__ __forceinline__ unsigned short f2bf(float f) {
    union { float f; unsigned u; } v; v.f = f;
    unsigned u = v.u + 0x7FFFu + ((v.u >> 16) & 1u);   // RNE
    return (unsigned short)(u >> 16);
}

// async global->LDS, 16B per lane, LDS dest = wave-uniform base + lane*16
__device__ __forceinline__ void gl_lds16(const unsigned short* g, unsigned short* l) {
    __builtin_amdgcn_global_load_lds(
        (const __attribute__((address_space(1))) void*)g,
        (__attribute__((address_space(3))) void*)l,
        16, 0, 0);
}

// --------------------------------------------- lens + fp32->bf16 convert ----
__global__ __launch_bounds__(256) void cvtlens_kernel(
    const float* __restrict__ inQ, const float* __restrict__ inK, const float* __restrict__ inV,
    const float* __restrict__ WQ, const float* __restrict__ WK,
    const float* __restrict__ WV, const float* __restrict__ WO,
    const int* __restrict__ rpm, const int* __restrict__ cpm,
    unsigned short* __restrict__ Xbf, unsigned short* __restrict__ Wbf,
    int* __restrict__ lens)
{
    const int t = threadIdx.x;
    if (blockIdx.x < 2) {
        __shared__ int red[256];
        const int b = blockIdx.x;
        int sr = 0, sc2 = 0;
        for (int i = t; i < S_LEN; i += 256) {
            sr  += rpm[b * S_LEN + i];
            sc2 += cpm[b * S_LEN + i];
        }
        red[t] = sr;
        __syncthreads();
        for (int off = 128; off > 0; off >>= 1) {
            if (t < off) red[t] += red[t + off];
            __syncthreads();
        }
        if (t == 0) lens[b * 2 + 0] = red[0];
        __syncthreads();
        red[t] = sc2;
        __syncthreads();
        for (int off = 128; off > 0; off >>= 1) {
            if (t < off) red[t] += red[t + off];
            __syncthreads();
        }
        if (t == 0) lens[b * 2 + 1] = red[0];
    }

    const int NXC = 786432;          // 3*4096*512/8
    const int NTOT = 917504;         // + 4*512*512/8
    const int stride = gridDim.x * 256;
    for (int c = blockIdx.x * 256 + t; c < NTOT; c += stride) {
        if (c < NXC) {
            const int flat = c << 3;
            const int z = flat >> 21;
            const int off = flat & 2097151;
            const float* src = ((z == 0) ? inQ : (z == 1) ? inK : inV) + off;
            float4 a = *(const float4*)src;
            float4 d = *(const float4*)(src + 4);
            unsigned short* w = Xbf + flat;
            w[0] = f2bf(a.x); w[1] = f2bf(a.y); w[2] = f2bf(a.z); w[3] = f2bf(a.w);
            w[4] = f2bf(d.x); w[5] = f2bf(d.y); w[6] = f2bf(d.z); w[7] = f2bf(d.w);
        } else {
            const int wflat = (c - NXC) << 3;
            const int wz = wflat >> 18;
            const int off = wflat & 262143;
            const float* src = ((wz == 0) ? WQ : (wz == 1) ? WK : (wz == 2) ? WV : WO) + off;
            float4 a = *(const float4*)src;
            float4 d = *(const float4*)(src + 4);
            unsigned short* w = Wbf + wflat;
            w[0] = f2bf(a.x); w[1] = f2bf(a.y); w[2] = f2bf(a.z); w[3] = f2bf(a.w);
            w[4] = f2bf(d.x); w[5] = f2bf(d.y); w[6] = f2bf(d.z); w[7] = f2bf(d.w);
        }
    }
}

// --------------------------------------------------------- projection GEMM --
// 128x128 tile, BK=64, DOUBLE-BUFFERED global_load_lds staging: prefetch for
// chunk kk+1 issued after the barrier, so the next barrier's vmcnt drain
// finds the loads already landed (overlap load latency with 32 MFMAs).
__global__ __launch_bounds__(256) void proj_gemm(
    const unsigned short* __restrict__ Xbf, const unsigned short* __restrict__ Wbf,
    const float* __restrict__ bQ, const float* __restrict__ bK, const float* __restrict__ bV,
    const int* __restrict__ lens,
    unsigned short* __restrict__ Qg, unsigned short* __restrict__ Kg,
    unsigned short* __restrict__ VTg)
{
    __shared__ __align__(16) unsigned short Xld[2][8192];
    __shared__ __align__(16) unsigned short Wld[2][8192];

    const int z = blockIdx.z;
    const int tileS = blockIdx.x * 128;
    const int tileF = blockIdx.y * 128;
    const int bb0 = tileS >> 11;
    const int rl = lens[bb0 * 2], cl = lens[bb0 * 2 + 1];
    const int limit = (z == 0) ? rl : cl;
    if ((tileS & 2047) >= limit) return;       // fully padded tile: outputs unused

    const unsigned short* X = Xbf + (size_t)z * (4096 * 512);
    const unsigned short* W = Wbf + (size_t)z * (512 * 512);
    const float* bias = (z == 0) ? bQ : (z == 1) ? bK : bV;

    const int t = threadIdx.x;
    const int wv = t >> 6, lane = t & 63, l15 = lane & 15, quad = lane >> 4;
    const int ro = lane >> 3;                 // row within 8-row staging group
    const int lc8 = ((lane & 7) ^ ro) * 8;    // swizzled source chunk (shorts)

    const unsigned short* gX = X + (size_t)(tileS + wv * 32 + ro) * 512 + lc8;
    const unsigned short* gW = W + (size_t)(tileF + wv * 32 + ro) * 512 + lc8;
    const int wvo = wv * 2048;

    const int f_off = (wv & 1) * 64, s_off = (wv >> 1) * 64;
    const int swk = l15 & 7;

    f32x4 acc[4][4] = {};

    // prologue: stage chunk 0 into buffer 0
    #pragma unroll
    for (int j = 0; j < 4; ++j) {
        gl_lds16(gX + j * 4096, &Xld[0][wvo + j * 512]);
        gl_lds16(gW + j * 4096, &Wld[0][wvo + j * 512]);
    }

    for (int kk = 0; kk < 8; ++kk) {
        __syncthreads();                       // drains chunk kk's loads
        if (kk < 7) {                          // prefetch chunk kk+1
            const int k0 = (kk + 1) * 64;
            const int nb = (kk + 1) & 1;
            #pragma unroll
            for (int j = 0; j < 4; ++j) {
                gl_lds16(gX + k0 + j * 4096, &Xld[nb][wvo + j * 512]);
                gl_lds16(gW + k0 + j * 4096, &Wld[nb][wvo + j * 512]);
            }
        }
        const unsigned short* Xb = Xld[kk & 1];
        const unsigned short* Wb = Wld[kk & 1];
        #pragma unroll
        for (int kk2 = 0; kk2 < 2; ++kk2) {
            bf16x8 wf[4], xf[4];
            #pragma unroll
            for (int i = 0; i < 4; ++i) {
                const int rw = f_off + i * 16 + l15;
                wf[i] = *(const bf16x8*)(Wb + rw * 64 + ((kk2 * 4 + quad) ^ swk) * 8);
                const int rx = s_off + i * 16 + l15;
                xf[i] = *(const bf16x8*)(Xb + rx * 64 + ((kk2 * 4 + quad) ^ swk) * 8);
            }
            #pragma unroll
            for (int ft = 0; ft < 4; ++ft)
                #pragma unroll
                for (int st = 0; st < 4; ++st)
                    acc[ft][st] = __builtin_amdgcn_mfma_f32_16x16x32_bf16(
                        wf[ft], xf[st], acc[ft][st], 0, 0, 0);
        }
    }

    const float oscale = (z == 0) ? 0.125f : 1.0f;   // fold 1/sqrt(dk) into Q
    #pragma unroll
    for (int ft = 0; ft < 4; ++ft) {
        const int f = tileF + f_off + ft * 16 + quad * 4;
        const int h = f >> 6, dk = f & 63;
        const float b0 = bias[f], b1 = bias[f + 1], b2 = bias[f + 2], b3 = bias[f + 3];
        #pragma unroll
        for (int st = 0; st < 4; ++st) {
            const int s = tileS + s_off + st * 16 + l15;
            const int bb = s >> 11, seq = s & 2047;
            const f32x4 a = acc[ft][st];
            if (z <= 1) {
                unsigned short* dst = ((z == 0) ? Qg : Kg)
                    + ((size_t)((bb * 8 + h) * 2048 + seq)) * 64 + dk;
                ushort4 u;
                u.x = f2bf((a[0] + b0) * oscale); u.y = f2bf((a[1] + b1) * oscale);
                u.z = f2bf((a[2] + b2) * oscale); u.w = f2bf((a[3] + b3) * oscale);
                *(ushort4*)dst = u;
            } else {
                unsigned short* dst = VTg
                    + ((size_t)((bb * 8 + h) * 64 + dk)) * 2048 + seq;
                dst[0]    = f2bf(a[0] + b0);
                dst[2048] = f2bf(a[1] + b1);
                dst[4096] = f2bf(a[2] + b2);
                dst[6144] = f2bf(a[3] + b3);
            }
        }
    }
}

// ----------------------------------------------------------- attention ------
// Flash-decoding, 4 waves split the kv loop. K and V^T tiles are staged into
// per-wave LDS via coalesced global_load_lds (XOR-swizzled addresses) — no
// block barriers in the loop; same-wave ordering via explicit s_waitcnt.
// V^T staging reuses the K region after K frags are read into registers.
__global__ __launch_bounds__(256) void attn_kernel(
    const unsigned short* __restrict__ Qg, const unsigned short* __restrict__ Kg,
    const unsigned short* __restrict__ VTg, const int* __restrict__ lens,
    unsigned short* __restrict__ AO)
{
    __shared__ __align__(16) char smem[32768 + 9216 + 512];
    unsigned short* stage = (unsigned short*)smem;              // 4 x 4096 shorts
    unsigned short* Plb   = (unsigned short*)(smem + 32768);    // 4 x 16 x 72
    float* Ml = (float*)(smem + 32768 + 9216);                  // 64
    float* Ll = Ml + 64;                                        // 64

    const int t = threadIdx.x;
    const int wv = t >> 6, lane = t & 63, l15 = lane & 15, quad = lane >> 4;
    const int bh = blockIdx.y;
    const int b = bh >> 3, h = bh & 7;
    const int q0 = blockIdx.x * 16;
    const int rl = lens[b * 2], cl = lens[b * 2 + 1];

    if (q0 >= rl) {                            // fully masked rows -> zeros
        const int row = t >> 4, cg = t & 15;
        ushort4 zz = {0, 0, 0, 0};
        *(ushort4*)(AO + ((size_t)(b * 2048 + q0 + row)) * 512 + h * 64 + cg * 4) = zz;
        return;
    }

    const unsigned short* Qrow = Qg + ((size_t)(bh * 2048 + q0 + l15)) * 64;
    const bf16x8 aq0 = *(const bf16x8*)(Qrow + quad * 8);
    const bf16x8 aq1 = *(const bf16x8*)(Qrow + 32 + quad * 8);

    unsigned short* stw = stage + wv * 4096;   // this wave's 8 KB tile buffer
    unsigned short* pb  = Plb + wv * (16 * 72);

    const int sro = lane >> 3;                     // staging row-in-group
    const int sc8 = ((lane & 7) ^ sro) * 8;        // swizzled chunk (shorts)
    const int kg_off  = sro * 64 + sc8;            // K per-lane src offset
    const int vtg_off = sro * 2048 + sc8;          // V^T per-lane src offset
    const int sw7 = l15 & 7;

    f32x4 oacc[4] = {};
    float m_[4], l_[4];
    #pragma unroll
    for (int r = 0; r < 4; ++r) { m_[r] = -__builtin_inff(); l_[r] = 0.f; }

    const int q_end = q0 + 16;
    const int kv_max = (cl < q_end) ? cl : q_end;
    const int ntiles = (kv_max + 63) >> 6;
    const int qrow0 = q0 + quad * 4;

    for (int kt = wv; kt < ntiles; kt += 4) {
        const int kv0 = kt * 64;

        {
            const unsigned short* kg = Kg + ((size_t)(bh * 2048 + kv0)) * 64 + kg_off;
            #pragma unroll
            for (int j = 0; j < 8; ++j)
                gl_lds16(kg + j * 512, stw + j * 512);
        }
        __builtin_amdgcn_s_waitcnt(0x0070);    // vmcnt(0)+lgkmcnt(0): K staged

        f32x4 sc[4] = {};
        #pragma unroll
        for (int ct = 0; ct < 4; ++ct) {
            const unsigned short* krow = stw + (ct * 16 + l15) * 64;
            const bf16x8 kf0 = *(const bf16x8*)(krow + ((quad    ) ^ sw7) * 8);
            const bf16x8 kf1 = *(const bf16x8*)(krow + ((quad + 4) ^ sw7) * 8);
            sc[ct] = __builtin_amdgcn_mfma_f32_16x16x32_bf16(aq0, kf0, sc[ct], 0, 0, 0);
            sc[ct] = __builtin_amdgcn_mfma_f32_16x16x32_bf16(aq1, kf1, sc[ct], 0, 0, 0);
        }
        __builtin_amdgcn_s_waitcnt(0x0070);    // K frag ds_reads done -> region free

        {
            const unsigned short* vg = VTg + ((size_t)(bh * 64)) * 2048 + kv0 + vtg_off;
            #pragma unroll
            for (int j = 0; j < 8; ++j)
                gl_lds16(vg + j * 16384, stw + j * 512);
        }

        const bool full = (kv0 + 64 <= q0) && (kv0 + 64 <= cl) && (q_end <= rl);

        #pragma unroll
        for (int r = 0; r < 4; ++r) {
            const int q = qrow0 + r;
            float mx = -__builtin_inff();
            if (full) {
                #pragma unroll
                for (int ct = 0; ct < 4; ++ct) mx = fmaxf(mx, sc[ct][r]);
            } else {
                #pragma unroll
                for (int ct = 0; ct < 4; ++ct) {
                    const int kv = kv0 + ct * 16 + l15;
                    float s = sc[ct][r];
                    const bool valid = (q < rl) && (kv < cl) && (kv <= q);
                    s = valid ? s : -__builtin_inff();
                    sc[ct][r] = s;
                    mx = fmaxf(mx, s);
                }
            }
            mx = fmaxf(mx, __shfl_xor(mx, 1, 16));
            mx = fmaxf(mx, __shfl_xor(mx, 2, 16));
            mx = fmaxf(mx, __shfl_xor(mx, 4, 16));
            mx = fmaxf(mx, __shfl_xor(mx, 8, 16));

            const float mold = m_[r];
            const float mnew = fmaxf(mold, mx);
            const float alpha = (mold == -__builtin_inff()) ? 0.f : __expf(mold - mnew);
            float psum = 0.f;
            #pragma unroll
            for (int ct = 0; ct < 4; ct++) {
                const float sv = sc[ct][r];
                const float p = (mnew == -__builtin_inff()) ? 0.f : __expf(sv - mnew);
                sc[ct][r] = p;
                psum += p;
            }
            psum += __shfl_xor(psum, 1, 16);
            psum += __shfl_xor(psum, 2, 16);
            psum += __shfl_xor(psum, 4, 16);
            psum += __shfl_xor(psum, 8, 16);
            l_[r] = alpha * l_[r] + psum;
            m_[r] = mnew;
            #pragma unroll
            for (int ct = 0; ct < 4; ct++) oacc[ct][r] *= alpha;
        }

        // P: C-layout -> A-layout via padded per-wave LDS (stride 72 shorts)
        #pragma unroll
        for (int ct = 0; ct < 4; ++ct) {
            #pragma unroll
            for (int r = 0; r < 4; ++r)
                pb[(quad * 4 + r) * 72 + ct * 16 + l15] = f2bf(sc[ct][r]);
        }
        const bf16x8 pf0 = *(const bf16x8*)(pb + l15 * 72 + quad * 8);
        const bf16x8 pf1 = *(const bf16x8*)(pb + l15 * 72 + 32 + quad * 8);

        __builtin_amdgcn_s_waitcnt(0x0070);    // V^T staged (and P ds ops done)
        #pragma unroll
        for (int ct = 0; ct < 4; ++ct) {
            const unsigned short* vrow = stw + (ct * 16 + l15) * 64;
            const bf16x8 vf0 = *(const bf16x8*)(vrow + ((quad    ) ^ sw7) * 8);
            const bf16x8 vf1 = *(const bf16x8*)(vrow + ((quad + 4) ^ sw7) * 8);
            oacc[ct] = __builtin_amdgcn_mfma_f32_16x16x32_bf16(pf0, vf0, oacc[ct], 0, 0, 0);
            oacc[ct] = __builtin_amdgcn_mfma_f32_16x16x32_bf16(pf1, vf1, oacc[ct], 0, 0, 0);
        }
    }

    // publish m,l partials (separate region, safe before barrier)
    if (l15 == 0) {
        #pragma unroll
        for (int r = 0; r < 4; ++r) {
            Ml[wv * 16 + quad * 4 + r] = m_[r];
            Ll[wv * 16 + quad * 4 + r] = l_[r];
        }
    }
    __syncthreads();                           // all waves done with staging

    // O partials alias the staging region (stride 68 floats: 2-way only)
    float* Po = (float*)smem;
    #pragma unroll
    for (int ct = 0; ct < 4; ++ct) {
        #pragma unroll
        for (int r = 0; r < 4; ++r)
            Po[wv * 1088 + (quad * 4 + r) * 68 + ct * 16 + l15] = oacc[ct][r];
    }
    __syncthreads();

    // merge 4 partials
    const int row = t >> 4, cg = t & 15;
    float mw[4];
    float mstar = -__builtin_inff();
    #pragma unroll
    for (int w = 0; w < 4; ++w) {
        mw[w] = Ml[w * 16 + row];
        mstar = fmaxf(mstar, mw[w]);
    }
    f32x4 o = {};
    if (mstar != -__builtin_inff()) {
        float lst = 0.f;
        #pragma unroll
        for (int w = 0; w < 4; ++w) {
            const float sw = (mw[w] == -__builtin_inff()) ? 0.f : __expf(mw[w] - mstar);
            lst += sw * Ll[w * 16 + row];
            const f32x4 pv = *(const f32x4*)&Po[w * 1088 + row * 68 + cg * 4];
            o[0] += sw * pv[0]; o[1] += sw * pv[1];
            o[2] += sw * pv[2]; o[3] += sw * pv[3];
        }
        const float inv = (lst > 0.f) ? 1.f / lst : 0.f;
        o[0] *= inv; o[1] *= inv; o[2] *= inv; o[3] *= inv;
    }
    ushort4 u;
    u.x = f2bf(o[0]); u.y = f2bf(o[1]); u.z = f2bf(o[2]); u.w = f2bf(o[3]);
    *(ushort4*)(AO + ((size_t)(b * 2048 + q0 + row)) * 512 + h * 64 + cg * 4) = u;
}

// ------------------------------------------------------------- output GEMM --
__global__ __launch_bounds__(256) void out_gemm(
    const unsigned short* __restrict__ AO, const unsigned short* __restrict__ Wbf,
    const float* __restrict__ bO, const int* __restrict__ lens, float* __restrict__ out)
{
    __shared__ __align__(16) unsigned short Xld[2][8192];
    __shared__ __align__(16) unsigned short Wld[2][8192];

    const int tileS = blockIdx.x * 128;
    const int tileF = blockIdx.y * 128;
    const int bb0 = tileS >> 11;
    const int rl = lens[bb0 * 2];
    const int t = threadIdx.x;

    if ((tileS & 2047) >= rl) {                // padded rows: out = bias
        const int r0 = t >> 2;
        const int cg = (t & 3) * 32;
        float4 bv[8];
        #pragma unroll
        for (int j = 0; j < 8; ++j) bv[j] = *(const float4*)(bO + tileF + cg + j * 4);
        #pragma unroll
        for (int i = 0; i < 2; ++i) {
            float* orow = out + (size_t)(tileS + i * 64 + r0) * 512 + tileF + cg;
            #pragma unroll
            for (int j = 0; j < 8; ++j) *(float4*)(orow + j * 4) = bv[j];
        }
        return;
    }

    const unsigned short* W = Wbf + (size_t)3 * (512 * 512);
    const int wv = t >> 6, lane = t & 63, l15 = lane & 15, quad = lane >> 4;
    const int ro = lane >> 3;
    const int lc8 = ((lane & 7) ^ ro) * 8;

    const unsigned short* gX = AO + (size_t)(tileS + wv * 32 + ro) * 512 + lc8;
    const unsigned short* gW = W + (size_t)(tileF + wv * 32 + ro) * 512 + lc8;
    const int wvo = wv * 2048;

    const int f_off = (wv & 1) * 64, s_off = (wv >> 1) * 64;
    const int swk = l15 & 7;

    f32x4 acc[4][4] = {};

    #pragma unroll
    for (int j = 0; j < 4; ++j) {
        gl_lds16(gX + j * 4096, &Xld[0][wvo + j * 512]);
        gl_lds16(gW + j * 4096, &Wld[0][wvo + j * 512]);
    }

    for (int kk = 0; kk < 8; ++kk) {
        __syncthreads();
        if (kk < 7) {
            const int k0 = (kk + 1) * 64;
            const int nb = (kk + 1) & 1;
            #pragma unroll
            for (int j = 0; j < 4; ++j) {
                gl_lds16(gX + k0 + j * 4096, &Xld[nb][wvo + j * 512]);
                gl_lds16(gW + k0 + j * 4096, &Wld[nb][wvo + j * 512]);
            }
        }
        const unsigned short* Xb = Xld[kk & 1];
        const unsigned short* Wb = Wld[kk & 1];
        #pragma unroll
        for (int kk2 = 0; kk2 < 2; ++kk2) {
            bf16x8 wf[4], xf[4];
            #pragma unroll
            for (int i = 0; i < 4; ++i) {
                const int rw = f_off + i * 16 + l15;
                wf[i] = *(const bf16x8*)(Wb + rw * 64 + ((kk2 * 4 + quad) ^ swk) * 8);
                const int rx = s_off + i * 16 + l15;
                xf[i] = *(const bf16x8*)(Xb + rx * 64 + ((kk2 * 4 + quad) ^ swk) * 8);
            }
            #pragma unroll
            for (int ft = 0; ft < 4; ++ft)
                #pragma unroll
                for (int st = 0; st < 4; ++st)
                    acc[ft][st] = __builtin_amdgcn_mfma_f32_16x16x32_bf16(
                        wf[ft], xf[st], acc[ft][st], 0, 0, 0);
        }
    }

    #pragma unroll
    for (int ft = 0; ft < 4; ++ft) {
        const int f = tileF + f_off + ft * 16 + quad * 4;
        const float4 bv = *(const float4*)(bO + f);
        #pragma unroll
        for (int st = 0; st < 4; ++st) {
            const int s = tileS + s_off + st * 16 + l15;
            float4 o;
            o.x = acc[ft][st][0] + bv.x;
            o.y = acc[ft][st][1] + bv.y;
            o.z = acc[ft][st][2] + bv.z;
            o.w = acc[ft][st][3] + bv.w;
            *(float4*)(out + (size_t)s * 512 + f) = o;
        }
    }
}

// -------------------------------------------------------------- launch ------
extern "C" void kernel_launch(void* const* d_in, const int* in_sizes, int n_in,
                              void* d_out, int out_size, void* d_ws, size_t ws_size,
                              hipStream_t stream)
{
    const float* inQ = (const float*)d_in[0];
    const float* inK = (const float*)d_in[1];
    const float* inV = (const float*)d_in[2];
    const int*   rpm = (const int*)d_in[3];
    const int*   cpm = (const int*)d_in[4];
    const float* WQ  = (const float*)d_in[5];
    const float* bQ  = (const float*)d_in[6];
    const float* WK  = (const float*)d_in[7];
    const float* bK  = (const float*)d_in[8];
    const float* WV  = (const float*)d_in[9];
    const float* bV  = (const float*)d_in[10];
    const float* WO  = (const float*)d_in[11];
    const float* bO  = (const float*)d_in[12];
    float* out = (float*)d_out;

    char* ws = (char*)d_ws;
    unsigned short* Xbf = (unsigned short*)(ws);                 // 12 MB
    unsigned short* Wbf = (unsigned short*)(ws + 12582912);      //  2 MB
    unsigned short* Qg  = (unsigned short*)(ws + 14680064);      //  4 MB
    unsigned short* Kg  = (unsigned short*)(ws + 18874368);      //  4 MB
    unsigned short* VTg = (unsigned short*)(ws + 23068672);      //  4 MB
    unsigned short* AO  = (unsigned short*)(ws + 27262976);      //  4 MB
    int* lens           = (int*)(ws + 31457280);

    cvtlens_kernel<<<dim3(1792), dim3(256), 0, stream>>>(
        inQ, inK, inV, WQ, WK, WV, WO, rpm, cpm, Xbf, Wbf, lens);
    proj_gemm<<<dim3(32, 4, 3), dim3(256), 0, stream>>>(
        Xbf, Wbf, bQ, bK, bV, lens, Qg, Kg, VTg);
    attn_kernel<<<dim3(128, 16), dim3(256), 0, stream>>>(Qg, Kg, VTg, lens, AO);
    out_gemm<<<dim3(32, 4), dim3(256), 0, stream>>>(AO, Wbf, bO, lens, out);
}